// Round 11
// baseline (975.329 us; speedup 1.0000x reference)
//
#include <hip/hip_runtime.h>
#include <hip/hip_bf16.h>

typedef __attribute__((ext_vector_type(8))) __bf16 bf16x8;
typedef __attribute__((ext_vector_type(4))) float f32x4;

#define NTOK 8192
#define D_DIM 1024
#define F_DIM 4096
#define NEXP 8
#define SLOT_TOT 16384          // 2 * NTOK
#define SLOT_CAP 16640          // SLOT_TOT + 256 padding (tile overrun)
#define TILE_MAX 136            // sum ceil(cnt_e/128) <= 128 + 8; 136 = 8*17

__device__ __forceinline__ unsigned short f2b(float f) {
  __hip_bfloat16 b = __float2bfloat16(f);
  return reinterpret_cast<unsigned short&>(b);
}

// tanh-form GELU (branch-free): max |err| vs exact erf-GELU ~3e-4.
__device__ __forceinline__ float gelu_f(float v) {
  const float y2 = v * (1.5957691216f + 0.0713548162f * v * v);
  return v * __builtin_amdgcn_rcpf(1.f + __expf(-y2));
}

__device__ __forceinline__ void gload_lds16(const void* g, void* l) {
  __builtin_amdgcn_global_load_lds(
      (__attribute__((address_space(1))) void*)g,
      (__attribute__((address_space(3))) void*)l, 16, 0, 0);
}

// ---------------- small kernels ----------------

__global__ void init_counts_kernel(int* counts) {
  if (threadIdx.x < NEXP) counts[threadIdx.x] = 0;
}

__global__ void zero_out_kernel(float* out) {
  const int i = blockIdx.x * 256 + threadIdx.x;
  reinterpret_cast<float4*>(out)[i] = make_float4(0.f, 0.f, 0.f, 0.f);
}

// fused scatter + gather: one block per token.
__global__ void scatter_gather_kernel(const float* __restrict__ x,
                                      const int* __restrict__ topk_idx,
                                      int* __restrict__ cursors,
                                      int* __restrict__ slot_pos,
                                      __hip_bfloat16* __restrict__ xg) {
  __shared__ int ps[2];
  const int tok = blockIdx.x;
  const int tid = threadIdx.x;
  if (tid < 2) {
    const int e = topk_idx[tok * 2 + tid];
    const int p = atomicAdd(&cursors[e], 1);
    slot_pos[tok * 2 + tid] = p;
    ps[tid] = p;
  }
  __syncthreads();
  const int d = tid * 4;
  const float4 v = *reinterpret_cast<const float4*>(x + (size_t)tok * D_DIM + d);
  union { unsigned short u[4]; uint2 q; } o;
  o.u[0] = f2b(v.x); o.u[1] = f2b(v.y); o.u[2] = f2b(v.z); o.u[3] = f2b(v.w);
  *reinterpret_cast<uint2*>(xg + (size_t)ps[0] * D_DIM + d) = o.q;
  *reinterpret_cast<uint2*>(xg + (size_t)ps[1] * D_DIM + d) = o.q;
}

// out[tok] = w0 * ys[s0] + w1 * ys[s1]   (bias already inside ys)
__global__ void combine_kernel(const __hip_bfloat16* __restrict__ ys,
                               const int* __restrict__ slot_pos,
                               const float* __restrict__ topk_w,
                               float* __restrict__ out) {
  const int tok = blockIdx.x;
  const int d = threadIdx.x * 4;
  const int s0 = slot_pos[tok * 2], s1 = slot_pos[tok * 2 + 1];
  const float w0 = topk_w[tok * 2], w1 = topk_w[tok * 2 + 1];
  union { unsigned short u[4]; uint2 q; } a, b;
  a.q = *reinterpret_cast<const uint2*>(ys + (size_t)s0 * D_DIM + d);
  b.q = *reinterpret_cast<const uint2*>(ys + (size_t)s1 * D_DIM + d);
  float4 rr;
  float va[4];
  #pragma unroll
  for (int i = 0; i < 4; ++i) {
    unsigned int ua = (unsigned int)a.u[i] << 16;
    unsigned int ub = (unsigned int)b.u[i] << 16;
    va[i] = w0 * reinterpret_cast<float&>(ua) + w1 * reinterpret_cast<float&>(ub);
  }
  rr.x = va[0]; rr.y = va[1]; rr.z = va[2]; rr.w = va[3];
  *reinterpret_cast<float4*>(out + (size_t)tok * D_DIM + d) = rr;
}

// src: per-expert [R][C] f32 -> dst: per-expert [C][R] bf16. 64x64 tile,
// 256 threads; float4 loads, uint4 (8x bf16, 16 B) stores.
__global__ void transpose_conv_kernel(const float* __restrict__ src,
                                      __hip_bfloat16* __restrict__ dst,
                                      int R, int C) {
  __shared__ float tile[64][65];
  const int e = blockIdx.z;
  src += (size_t)e * R * C;
  dst += (size_t)e * R * C;
  const int c0 = blockIdx.x * 64, r0 = blockIdx.y * 64;
  const int tid = threadIdx.x;
  const int lr = tid >> 4, lc4 = (tid & 15) * 4;
  #pragma unroll
  for (int pass = 0; pass < 4; ++pass) {
    const int rr = pass * 16 + lr;
    const float4 v = *reinterpret_cast<const float4*>(
        &src[(size_t)(r0 + rr) * C + c0 + lc4]);
    tile[rr][lc4 + 0] = v.x; tile[rr][lc4 + 1] = v.y;
    tile[rr][lc4 + 2] = v.z; tile[rr][lc4 + 3] = v.w;
  }
  __syncthreads();
  const int sc = tid >> 3, sr8 = (tid & 7) * 8;
  #pragma unroll
  for (int pass = 0; pass < 2; ++pass) {
    const int c = pass * 32 + sc;
    union { unsigned short u[8]; uint4 q; } o;
    #pragma unroll
    for (int i = 0; i < 8; ++i) o.u[i] = f2b(tile[sr8 + i][c]);
    *reinterpret_cast<uint4*>(&dst[(size_t)(c0 + c) * R + r0 + sr8]) = o.q;
  }
}

// ---------------- router ----------------
__global__ void router_kernel(const float* __restrict__ x,
                              const float* __restrict__ rw,
                              const float* __restrict__ rb,
                              int* __restrict__ topk_idx,
                              float* __restrict__ topk_w,
                              int* __restrict__ counts) {
  __shared__ float rwT[NEXP * D_DIM];   // transposed [e][d], 32 KB
  const int tid = threadIdx.x;
  for (int i = tid; i < NEXP * D_DIM; i += 256) {
    const int d = i >> 3, e = i & 7;
    rwT[e * D_DIM + d] = rw[i];
  }
  __syncthreads();

  const int wave = tid >> 6, lane = tid & 63;
  const int tok = blockIdx.x * 4 + wave;
  const float* xr = x + (size_t)tok * D_DIM;

  float acc[NEXP];
  #pragma unroll
  for (int e = 0; e < NEXP; ++e) acc[e] = 0.f;

  for (int i = 0; i < D_DIM / 64; ++i) {
    const int d = i * 64 + lane;
    const float xv = xr[d];
    #pragma unroll
    for (int e = 0; e < NEXP; ++e) acc[e] += xv * rwT[e * D_DIM + d];
  }
  #pragma unroll
  for (int off = 32; off > 0; off >>= 1) {
    #pragma unroll
    for (int e = 0; e < NEXP; ++e) acc[e] += __shfl_xor(acc[e], off);
  }

  if (lane == 0) {
    float l[NEXP];
    #pragma unroll
    for (int e = 0; e < NEXP; ++e) l[e] = acc[e] + rb[e];
    int i1 = 0;
    #pragma unroll
    for (int e = 1; e < NEXP; ++e) if (l[e] > l[i1]) i1 = e;
    int i2 = (i1 == 0) ? 1 : 0;
    #pragma unroll
    for (int e = 0; e < NEXP; ++e) if (e != i1 && e != i2 && l[e] > l[i2]) i2 = e;
    const float w1 = 1.f / (1.f + __expf(l[i2] - l[i1]));
    topk_idx[tok * 2 + 0] = i1;
    topk_idx[tok * 2 + 1] = i2;
    topk_w[tok * 2 + 0] = w1;
    topk_w[tok * 2 + 1] = 1.f - w1;
    atomicAdd(&counts[i1], 1);
    atomicAdd(&counts[i2], 1);
  }
}

// builds offsets, cursors, and the compact (expert, mt) tile table (BM=128)
__global__ void offsets_kernel(const int* __restrict__ counts,
                               int* __restrict__ offsets,
                               int* __restrict__ cursors,
                               int* __restrict__ tile_meta) {
  if (threadIdx.x == 0) {
    int s = 0;
    for (int e = 0; e < NEXP; ++e) { offsets[e] = s; cursors[e] = s; s += counts[e]; }
    offsets[NEXP] = s;
    int n = 0;
    for (int e = 0; e < NEXP; ++e) {
      const int ntile = (counts[e] + 127) >> 7;
      for (int m = 0; m < ntile && n < TILE_MAX; ++m) tile_meta[n++] = e | (m << 8);
    }
    for (; n < TILE_MAX; ++n) tile_meta[n] = 0 | (1 << 22);   // mt huge -> exits
  }
}

// ---------------- MFMA GEMMs: 128x256, XCD-grouped, T3-minimum ----------------
// BM=128, BN=256, BK=32, 512 threads = 8 waves (2M x 4N), wave tile 64x64,
// acc[4][4] (64 AGPR + ~56 VGPR ~= 120 <= 128) -> 4 waves/SIMD -> 2 blocks/CU.
// (r10 lesson: acc[8][4] tiles are register-capped at 1 blk/CU -> staging rate
// collapses to ~3.5 TB/s; 2+ blk/CU sustains ~6.3.)
// LDS per buf: A 8 KB (8 chunks) + B 16 KB (16 chunks) = 24 KB; 2 bufs = 48 KB.
// Schedule (T3-minimum, m230): stage(next) -> compute(cur) -> __syncthreads().
// XCD-grouped decode (T1, bijective): xcd = bid&7, local = bid>>3,
//   j = xcd*17 + local/NT, nt = local%NT
// -> the NT nt-sharers of each A-tile are consecutive wgids on ONE XCD: the
// A tile is HBM-fetched once per XCD-visit and L2-shared (r10's nt-fastest
// round-robin put sharers on 8 different XCDs -> FETCH 668 MB).
template <int PHASE>
__global__ __launch_bounds__(512, 4) void moe_gemm(
    const __hip_bfloat16* __restrict__ A,   // [SLOT_CAP][K] slot-ordered
    const __hip_bfloat16* __restrict__ B,   // [NEXP][NCOL][K]
    const float* __restrict__ bias,         // [NEXP][NCOL]
    const int* __restrict__ counts,
    const int* __restrict__ offsets,
    const int* __restrict__ tile_meta,
    __hip_bfloat16* __restrict__ Cout) {    // [SLOT_CAP][NCOL]
  constexpr int K    = (PHASE == 1) ? D_DIM : F_DIM;
  constexpr int NCOL = (PHASE == 1) ? F_DIM : D_DIM;
  constexpr int NTSH = (PHASE == 1) ? 4 : 2;   // NT = 16 or 4
  constexpr int KT   = K / 32;

  const int xcd = blockIdx.x & 7;
  const int local = blockIdx.x >> 3;
  const int j = xcd * (TILE_MAX / 8) + (local >> NTSH);
  const int nt = local & ((1 << NTSH) - 1);
  const int meta = tile_meta[j];
  const int e = meta & 255, mt = meta >> 8;
  const int cnt = counts[e];
  if (mt * 128 >= cnt) return;
  const int base = offsets[e];

  __shared__ unsigned short lds[2][12288];  // per buf: A [0,4096) | B [4096,12288)

  const int tid = threadIdx.x;
  const int w = tid >> 6, lane = tid & 63;
  const int r = lane & 15, kg = lane >> 4;
  const int wm = w >> 2, wn = w & 3;        // 2M x 4N wave grid

  // wave w stages A chunk {w} and B chunks {w, w+8} (3 gload_lds / step).
  // chunk c (1 KB) = rows c*16+(lane&15), k=(lane>>4)*8..+8 at lane*16 B
  // (gload-linear; ds_read_b128 conflict-free, measured 0).
  const __hip_bfloat16* gA0 = A + (size_t)(base + mt * 128 + w * 16 + r) * K + kg * 8;
  const __hip_bfloat16* gB0 = B + ((size_t)e * NCOL + nt * 256 + w * 16 + r) * K + kg * 8;
  const __hip_bfloat16* gB1 = gB0 + (size_t)128 * K;

  f32x4 acc[4][4] = {};

  auto stage = [&](unsigned short* buf) {
    gload_lds16(gA0, buf + w * 512);
    gload_lds16(gB0, buf + 4096 + w * 512);
    gload_lds16(gB1, buf + 4096 + (w + 8) * 512);
    gA0 += 32; gB0 += 32; gB1 += 32;
  };
  auto compute = [&](const unsigned short* buf) {
    bf16x8 af[4], bfr[4];
    #pragma unroll
    for (int i2 = 0; i2 < 4; ++i2) {
      af[i2]  = *(const bf16x8*)(buf + (wm * 4 + i2) * 512 + lane * 8);
      bfr[i2] = *(const bf16x8*)(buf + 4096 + (wn * 4 + i2) * 512 + lane * 8);
    }
    #pragma unroll
    for (int mi = 0; mi < 4; ++mi)
      #pragma unroll
      for (int ni = 0; ni < 4; ++ni)
        acc[mi][ni] = __builtin_amdgcn_mfma_f32_16x16x32_bf16(
            af[mi], bfr[ni], acc[mi][ni], 0, 0, 0);
  };

  unsigned short* pc = lds[0];
  unsigned short* pn = lds[1];

  stage(pc);
  __syncthreads();                       // prologue: tile 0 resident
  for (int t = 0; t < KT - 1; ++t) {
    stage(pn);                           // issue next tile (overlaps compute)
    compute(pc);                         // 8 ds_read + 16 MFMA, free interleave
    __syncthreads();                     // one barrier: pn resident, pc free
    unsigned short* ts = pc; pc = pn; pn = ts;
  }
  compute(pc);                           // last tile

  // ---- epilogue (branch-free GELU; full-tile fast path) ----
  const int rem = cnt - mt * 128;
  const int q4 = (lane >> 4) * 4;
  const int c15 = lane & 15;

  if (rem >= 128) {                      // wave-uniform common path
    #pragma unroll
    for (int n = 0; n < 4; ++n) {
      const int col = nt * 256 + wn * 64 + n * 16 + c15;
      const float bv = bias[e * NCOL + col];
      #pragma unroll
      for (int m = 0; m < 4; ++m) {
        #pragma unroll
        for (int rr = 0; rr < 4; ++rr) {
          const int rloc = wm * 64 + m * 16 + q4 + rr;
          float v = acc[m][n][rr] + bv;
          if constexpr (PHASE == 1) v = gelu_f(v);
          Cout[(size_t)(base + mt * 128 + rloc) * NCOL + col] = __float2bfloat16(v);
        }
      }
    }
  } else {
    #pragma unroll
    for (int n = 0; n < 4; ++n) {
      const int col = nt * 256 + wn * 64 + n * 16 + c15;
      const float bv = bias[e * NCOL + col];
      #pragma unroll
      for (int m = 0; m < 4; ++m) {
        #pragma unroll
        for (int rr = 0; rr < 4; ++rr) {
          const int rloc = wm * 64 + m * 16 + q4 + rr;
          if (rloc < rem) {
            float v = acc[m][n][rr] + bv;
            if constexpr (PHASE == 1) v = gelu_f(v);
            Cout[(size_t)(base + mt * 128 + rloc) * NCOL + col] = __float2bfloat16(v);
          }
        }
      }
    }
  }
}

// ---------------- launch ----------------

extern "C" void kernel_launch(void* const* d_in, const int* in_sizes, int n_in,
                              void* d_out, int out_size, void* d_ws, size_t ws_size,
                              hipStream_t stream) {
  const float* x  = (const float*)d_in[0];
  const float* rw = (const float*)d_in[1];
  const float* rb = (const float*)d_in[2];
  const float* w1 = (const float*)d_in[3];
  const float* b1 = (const float*)d_in[4];
  const float* w2 = (const float*)d_in[5];
  const float* b2 = (const float*)d_in[6];
  float* out = (float*)d_out;

  char* p = (char*)d_ws;
  size_t used = 0;
  auto carve = [&](size_t bytes) {
    char* r = p + used;
    used += (bytes + 255) & ~(size_t)255;
    return (void*)r;
  };
  __hip_bfloat16* xg  = (__hip_bfloat16*)carve((size_t)SLOT_CAP * D_DIM * 2);
  __hip_bfloat16* ys  = xg;   // alias: xg dead after GEMM1
  __hip_bfloat16* w1t = (__hip_bfloat16*)carve((size_t)NEXP * F_DIM * D_DIM * 2);
  __hip_bfloat16* w2t = (__hip_bfloat16*)carve((size_t)NEXP * D_DIM * F_DIM * 2);
  __hip_bfloat16* h   = (__hip_bfloat16*)carve((size_t)SLOT_CAP * F_DIM * 2);
  int*   topk_idx   = (int*)carve((size_t)NTOK * 2 * 4);
  float* topk_w     = (float*)carve((size_t)NTOK * 2 * 4);
  int*   slot_pos   = (int*)carve((size_t)NTOK * 2 * 4);
  int*   tile_meta  = (int*)carve(TILE_MAX * 4);
  int* counts  = (int*)carve(256);
  int* offsets = (int*)carve(256);
  int* cursors = (int*)carve(256);

  if (used > ws_size) {   // guard: deterministic zero output, diagnosable
    zero_out_kernel<<<8192, 256, 0, stream>>>(out);
    return;
  }

  init_counts_kernel<<<1, 64, 0, stream>>>(counts);
  router_kernel<<<NTOK / 4, 256, 0, stream>>>(x, rw, rb, topk_idx, topk_w, counts);
  offsets_kernel<<<1, 64, 0, stream>>>(counts, offsets, cursors, tile_meta);
  scatter_gather_kernel<<<NTOK, 256, 0, stream>>>(x, topk_idx, cursors, slot_pos, xg);

  transpose_conv_kernel<<<dim3(F_DIM / 64, D_DIM / 64, NEXP), 256, 0, stream>>>(
      w1, w1t, D_DIM, F_DIM);
  transpose_conv_kernel<<<dim3(D_DIM / 64, F_DIM / 64, NEXP), 256, 0, stream>>>(
      w2, w2t, F_DIM, D_DIM);

  // grids: TILE_MAX * NT; decode inside is XCD-grouped (bijective, m204-style)
  moe_gemm<1><<<TILE_MAX * (F_DIM / 256), 512, 0, stream>>>(
      xg, w1t, b1, counts, offsets, tile_meta, h);
  moe_gemm<2><<<TILE_MAX * (D_DIM / 256), 512, 0, stream>>>(
      h, w2t, b2, counts, offsets, tile_meta, ys);

  combine_kernel<<<NTOK, 256, 0, stream>>>(ys, slot_pos, topk_w, out);
}